// Round 18
// baseline (462.207 us; speedup 1.0000x reference)
//
#include <hip/hip_runtime.h>
#include <hip/hip_bf16.h>

// QJLSketch: H=32, G=128, N=64, D=128, S=256, K=8
// d_out (float32, concatenated):
//   [0,        8388608): hash_inlier  [32,128,64,32] byte values as floats
//   [8388608, 12582912): hash_outlier [32,128,64,16] byte values as floats
//   [12582912,12845056): scores       [32, 128*64]
//
// Strategy: bf16 hi/lo split MFMA GEMM (fast approx) + exact f32-chain fixup for
// |value| < EPS. Non-flagged signs provably match the reference's sequential
// f32 FMA chain; flagged ones recomputed with the verified chain semantics.
// R18 = R15 + q-split GEMM: true register usage was VGPR 84 + AGPR 64 (acc[16]
// f32x4) = 148 -> 3 waves/SIMD cap (rocprof VGPR_Count excludes AGPRs on the
// unified gfx950 file). Splitting into two q-halves (acc[8] = 32 AGPR,
// #pragma unroll 1) drops live state to ~117 <= 128, so launch_bounds(256,4)
// fits WITHOUT the allocator squeeze that spilled R10/R13/R14 (cap < live).
// LDS 39936B x 4 = 159.7KB fits -> 4 blocks/CU = 16 waves (was 12).

typedef __attribute__((ext_vector_type(8))) short short8;
typedef __attribute__((ext_vector_type(4))) float f32x4;

constexpr int cH = 32, cG = 128, cN = 64, cD = 128, cS = 256, cK = 8;
constexpr int HASH_OUT_BASE = cH * cG * cN * (cS / 8);                  // 8388608
constexpr int SCORE_BASE    = HASH_OUT_BASE + cH * cG * cN * (cS / 16); // 12582912
constexpr float EPS_IN  = 1e-3f;
constexpr float EPS_OUT = 1e-3f;
constexpr size_t WS_BHI = 32768, WS_BLO = 98304, WS_NEED = 163840;

#define MFMA(a, b, c) __builtin_amdgcn_mfma_f32_16x16x32_bf16(a, b, c, 0, 0, 0)

// Integer RNE f32->bf16 (valid for all finite x; data is N(0,1), no NaN/Inf).
__device__ inline short f2bf(float x) {
    unsigned u = __builtin_bit_cast(unsigned, x);
    u += 0x7FFFu + ((u >> 16) & 1u);
    return (short)(u >> 16);
}
__device__ inline float bf2f(short s) {
    return __builtin_bit_cast(float, (unsigned)((unsigned short)s) << 16);
}
__device__ inline unsigned long long sel4(unsigned long long a0, unsigned long long a1,
                                          unsigned long long a2, unsigned long long a3, int r) {
    unsigned long long x = a0;
    x = (r == 1) ? a1 : x; x = (r == 2) ? a2 : x; x = (r == 3) ? a3 : x;
    return x;
}
__device__ inline int sel8(const int* u, int k) {
    int x = u[0];
    x = (k == 1) ? u[1] : x; x = (k == 2) ? u[2] : x; x = (k == 3) ? u[3] : x;
    x = (k == 4) ? u[4] : x; x = (k == 5) ? u[5] : x; x = (k == 6) ? u[6] : x;
    x = (k == 7) ? u[7] : x;
    return x;
}
#define CE(i, j) { int a = u[i], b = u[j]; u[i] = min(a, b); u[j] = max(a, b); }

#define SORT8_AND_MASK(oidx_ptr, bb)                                   \
    int u[cK];                                                         \
    _Pragma("unroll")                                                  \
    for (int k = 0; k < cK; ++k) u[k] = (oidx_ptr)[(bb) * cK + k];     \
    unsigned long long m0 = 0, m1 = 0;                                 \
    _Pragma("unroll")                                                  \
    for (int k = 0; k < cK; ++k) {                                     \
        int v = u[k];                                                  \
        if (v < 64) m0 |= 1ull << v; else m1 |= 1ull << (v - 64);      \
    }                                                                  \
    CE(0,1) CE(2,3) CE(4,5) CE(6,7)                                    \
    CE(0,2) CE(1,3) CE(4,6) CE(5,7)                                    \
    CE(1,2) CE(5,6)                                                    \
    CE(0,4) CE(1,5) CE(2,6) CE(3,7)                                    \
    CE(2,4) CE(3,5)                                                    \
    CE(1,2) CE(3,4) CE(5,6)

// Exact reference chain for one (row,s) inlier value (rare). Vectorized.
__device__ __attribute__((noinline)) float exact_inlier(
    const float* __restrict__ dr, const float* __restrict__ pr,
    unsigned long long m0, unsigned long long m1)
{
    float ex = 0.0f;
    #pragma unroll 1
    for (int dc = 0; dc < 4; ++dc) {
        float4 da[8], pa[8];
        #pragma unroll
        for (int j = 0; j < 8; ++j) {
            da[j] = reinterpret_cast<const float4*>(dr)[dc * 8 + j];
            pa[j] = reinterpret_cast<const float4*>(pr)[dc * 8 + j];
        }
        #pragma unroll
        for (int j = 0; j < 8; ++j) {
            float dv[4] = { da[j].x, da[j].y, da[j].z, da[j].w };
            float pv[4] = { pa[j].x, pa[j].y, pa[j].z, pa[j].w };
            #pragma unroll
            for (int e = 0; e < 4; ++e) {
                const int d = dc * 32 + j * 4 + e;
                const bool msk = ((((d < 64) ? (m0 >> d) : (m1 >> (d - 64))) & 1ull) != 0);
                ex = fmaf(dv[e], msk ? 0.0f : pv[e], ex);
            }
        }
    }
    return ex;
}

// --- precompute: sketched_q[h][s] (sequential chain; scores have 2% tol) ---
__global__ __launch_bounds__(256) void qjl_qv(
    const float* __restrict__ query, const float* __restrict__ projs,
    float* __restrict__ qv_out)
{
    const int h = blockIdx.x, s = threadIdx.x;
    float qa = 0.0f;
    for (int d = 0; d < cD; ++d)
        qa = fmaf(query[h * cD + d], projs[d * cS + s], qa);
    qv_out[h * cS + s] = qa;
}

// --- precompute: B fragments (projq hi/lo bf16) in MFMA lane order ---
__global__ __launch_bounds__(256) void qjl_bfrag(
    const float* __restrict__ projq, short* __restrict__ bhi, short* __restrict__ blo)
{
    const int idx = blockIdx.x * 256 + threadIdx.x;    // [0, 4096)
    const int l = idx & 63, nt = (idx >> 6) & 15, ksub = idx >> 10;
    const int s = nt * 16 + (l & 15);
    const int k0 = ksub * 32 + (l >> 4) * 8;
    #pragma unroll
    for (int j = 0; j < 8; ++j) {
        float x = projq[s * cD + k0 + j];
        short h = f2bf(x);
        bhi[idx * 8 + j] = h;
        blo[idx * 8 + j] = f2bf(x - bf2f(h));
    }
}

__global__ __launch_bounds__(256, 4) void qjl_mfma(
    const float* __restrict__ data, const int* __restrict__ oidx,
    const float* __restrict__ norm_data, const float* __restrict__ projq,
    const float* __restrict__ qv_ws, const short* __restrict__ bhi_ws,
    const short* __restrict__ blo_ws, float* __restrict__ out)
{
    const int b    = blockIdx.x;      // h*G + g
    const int t    = threadIdx.x;
    const int lane = t & 63;
    const int w    = t >> 6;          // wave owns nt = 4w..4w+3 (s in [64w, 64w+64))
    const int c0   = lane & 15;
    const int g16  = lane >> 4;
    const int h    = b >> 7;

    __shared__ short A_hi[16 * 64 * 8];     // 16 KB  [(ksub*4+mt)*64+l]*8  (MASKED data)
    __shared__ short A_lo[16 * 64 * 8];     // 16 KB
    __shared__ float dO[cK * cN];           // 2 KB   [k][row]
    __shared__ float pO[cK * 128];          // 4 KB   [k][s<128] (outlier path only)
    __shared__ float ipPart[cN * 4];        // 1 KB   [row][wave]
    // total 39936 B -> 4 blocks/CU fits (159.7KB)

    const f32x4 zero4 = { 0.f, 0.f, 0.f, 0.f };

    SORT8_AND_MASK(oidx, b)
    const float* __restrict__ chunk = data + (size_t)b * (cN * cD);

    // --- stage A (masked, hi/lo) in fragment slot order: 4 slots/thread ---
    #pragma unroll
    for (int i = 0; i < 4; ++i) {
        const int slot = i * 256 + t;       // 1024 slots of 16B
        const int l = slot & 63, frag = slot >> 6;
        const int mt = frag & 3, ksub = frag >> 2;
        const int row = mt * 16 + (l & 15);
        const int k0 = ksub * 32 + (l >> 4) * 8;
        const float4* p = reinterpret_cast<const float4*>(chunk + row * cD + k0);
        float4 v0 = p[0], v1 = p[1];
        float xs[8] = { v0.x, v0.y, v0.z, v0.w, v1.x, v1.y, v1.z, v1.w };
        const unsigned bits = (unsigned)(((k0 < 64) ? (m0 >> k0) : (m1 >> (k0 - 64))) & 0xFFull);
        short hs[8], ls[8];
        #pragma unroll
        for (int e = 0; e < 8; ++e) {
            float x = ((bits >> e) & 1u) ? 0.0f : xs[e];   // key_inlier = data*(1-mask)
            hs[e] = f2bf(x);
            ls[e] = f2bf(x - bf2f(hs[e]));
        }
        *reinterpret_cast<short8*>(&A_hi[slot * 8]) =
            short8{ hs[0], hs[1], hs[2], hs[3], hs[4], hs[5], hs[6], hs[7] };
        *reinterpret_cast<short8*>(&A_lo[slot * 8]) =
            short8{ ls[0], ls[1], ls[2], ls[3], ls[4], ls[5], ls[6], ls[7] };
    }
    // --- stage dO[k][row] (512 elems, 2/thread) ---
    #pragma unroll
    for (int i = 0; i < 2; ++i) {
        const int idx = i * 256 + t;
        const int k = idx >> 6, row = idx & 63;
        dO[idx] = chunk[row * cD + sel8(u, k)];
    }
    // --- stage pO[k][s<128] (1024 elems, 4/thread; dup slots -> 0) ---
    #pragma unroll
    for (int i = 0; i < 4; ++i) {
        const int idx = i * 256 + t;
        const int k = idx >> 7, s = idx & 127;
        const int uk = sel8(u, k);
        const bool dup = (k > 0) && (uk == sel8(u, k - 1));
        float x = projq[s * cD + uk];
        pO[idx] = dup ? 0.0f : x;
    }
    __syncthreads();

    // --- outlier path: only waves 0,1 (s < 128) ---
    if (w < 2) {
        short8 aO[4];
        #pragma unroll
        for (int mt = 0; mt < 4; ++mt) {
            short v8[8];
            #pragma unroll
            for (int k = 0; k < cK; ++k) {
                float x = dO[k * cN + mt * 16 + c0];
                short hi = f2bf(x), lo = f2bf(x - bf2f(hi));
                v8[k] = (g16 == 2) ? lo : ((g16 == 3) ? (short)0 : hi);
            }
            aO[mt] = short8{ v8[0], v8[1], v8[2], v8[3], v8[4], v8[5], v8[6], v8[7] };
        }
        short8 bO[4];
        #pragma unroll
        for (int q = 0; q < 4; ++q) {
            const int s = (w * 4 + q) * 16 + c0;
            short v8[8];
            #pragma unroll
            for (int k = 0; k < cK; ++k) {
                float x = pO[k * 128 + s];
                short hi = f2bf(x), lo = f2bf(x - bf2f(hi));
                v8[k] = (g16 == 1) ? lo : ((g16 == 3) ? (short)0 : hi);
            }
            bO[q] = short8{ v8[0], v8[1], v8[2], v8[3], v8[4], v8[5], v8[6], v8[7] };
        }
        #pragma unroll
        for (int mt = 0; mt < 4; ++mt) {
            #pragma unroll
            for (int q = 0; q < 4; ++q) {
                f32x4 accO = MFMA(aO[mt], bO[q], zero4);
                unsigned long long b0, b1, b2, b3;
                #pragma unroll
                for (int r = 0; r < 4; ++r) {
                    float v = accO[r];
                    if (fabsf(v) < EPS_OUT) {
                        int row = mt * 16 + 4 * g16 + r;
                        int s = (w * 4 + q) * 16 + c0;
                        float o = 0.0f;
                        #pragma unroll
                        for (int k = 0; k < cK; ++k)
                            o = fmaf(dO[k * cN + row], pO[k * 128 + s], o);
                        v = o;
                    }
                    unsigned long long bal = __ballot(v > 0.0f);
                    if (r == 0) b0 = bal; else if (r == 1) b1 = bal;
                    else if (r == 2) b2 = bal; else b3 = bal;
                }
                if (lane < 32) {
                    int r = lane & 3, g = (lane >> 2) & 3, hb = lane >> 4;
                    unsigned long long bb = sel4(b0, b1, b2, b3, r);
                    int row = mt * 16 + 4 * g + r;
                    out[HASH_OUT_BASE + (size_t)b * (cN * 16) + row * 16 + (w * 4 + q) * 2 + hb] =
                        (float)((bb >> (16 * g + 8 * hb)) & 0xFFull);
                }
            }
        }
    }

    // --- inlier GEMM + epilogue in TWO q-halves (acc[8] = 32 AGPR each) ---
    #pragma unroll 1
    for (int qh = 0; qh < 2; ++qh) {
        f32x4 acc[8];
        #pragma unroll
        for (int i = 0; i < 8; ++i)
            acc[i] = zero4;

        #pragma unroll
        for (int ksub = 0; ksub < 4; ++ksub) {
            short8 ah[4], al[4];
            #pragma unroll
            for (int mt = 0; mt < 4; ++mt) {
                ah[mt] = *reinterpret_cast<const short8*>(&A_hi[((ksub * 4 + mt) * 64 + lane) * 8]);
                al[mt] = *reinterpret_cast<const short8*>(&A_lo[((ksub * 4 + mt) * 64 + lane) * 8]);
            }
            #pragma unroll
            for (int qq = 0; qq < 2; ++qq) {
                const int q = qh * 2 + qq;
                short8 bh = *reinterpret_cast<const short8*>(
                    &bhi_ws[((ksub * 16 + w * 4 + q) * 64 + lane) * 8]);
                #pragma unroll
                for (int mt = 0; mt < 4; ++mt)
                    acc[mt * 2 + qq] = MFMA(ah[mt], bh, acc[mt * 2 + qq]);
                short8 bl = *reinterpret_cast<const short8*>(
                    &blo_ws[((ksub * 16 + w * 4 + q) * 64 + lane) * 8]);
                #pragma unroll
                for (int mt = 0; mt < 4; ++mt)
                    acc[mt * 2 + qq] = MFMA(ah[mt], bl, acc[mt * 2 + qq]);
                #pragma unroll
                for (int mt = 0; mt < 4; ++mt)
                    acc[mt * 2 + qq] = MFMA(al[mt], bh, acc[mt * 2 + qq]);
            }
        }

        // epilogue for this half: fixup + hash stores + ip partials
        float qvv[2];
        #pragma unroll
        for (int qq = 0; qq < 2; ++qq)
            qvv[qq] = qv_ws[h * cS + (w * 4 + qh * 2 + qq) * 16 + c0];

        #pragma unroll
        for (int mt = 0; mt < 4; ++mt) {
            float part[4] = { 0.f, 0.f, 0.f, 0.f };
            #pragma unroll
            for (int qq = 0; qq < 2; ++qq) {
                const int q = qh * 2 + qq;
                unsigned long long b0, b1, b2, b3;
                #pragma unroll
                for (int r = 0; r < 4; ++r) {
                    float v = acc[mt * 2 + qq][r];
                    if (fabsf(v) < EPS_IN) {
                        int row = mt * 16 + 4 * g16 + r;
                        int s = (w * 4 + q) * 16 + c0;
                        v = exact_inlier(chunk + row * cD, projq + s * cD, m0, m1);
                    }
                    bool bit = v > 0.0f;
                    unsigned long long bal = __ballot(bit);
                    part[r] += bit ? qvv[qq] : -qvv[qq];
                    if (r == 0) b0 = bal; else if (r == 1) b1 = bal;
                    else if (r == 2) b2 = bal; else b3 = bal;
                }
                if (lane < 32) {
                    int r = lane & 3, g = (lane >> 2) & 3, hb = lane >> 4;
                    unsigned long long bb = sel4(b0, b1, b2, b3, r);
                    int row = mt * 16 + 4 * g + r;
                    out[(size_t)b * (cN * 32) + row * 32 + (w * 4 + q) * 2 + hb] =
                        (float)((bb >> (16 * g + 8 * hb)) & 0xFFull);
                }
            }
            #pragma unroll
            for (int r = 0; r < 4; ++r) {
                float x = part[r];
                x += __shfl_xor(x, 1); x += __shfl_xor(x, 2);
                x += __shfl_xor(x, 4); x += __shfl_xor(x, 8);
                if (c0 == 0) {
                    const int idx = (mt * 16 + 4 * g16 + r) * 4 + w;
                    // same thread writes then accumulates across halves: no race
                    ipPart[idx] = (qh == 0) ? x : (ipPart[idx] + x);
                }
            }
        }
    }
    __syncthreads();
    if (t < cN) {
        float ip = ipPart[t * 4 + 0] + ipPart[t * 4 + 1]
                 + ipPart[t * 4 + 2] + ipPart[t * 4 + 3];
        const float scl = 0.0048957583f;   // sqrt(pi/2)/256
        out[SCORE_BASE + (size_t)b * cN + t] = scl * norm_data[b * cN + t] * ip;
    }
}

// ---------------- fallback (R3 kernel, passed): used if ws too small ----------------
__global__ __launch_bounds__(256) void qjl_valu(
    const float* __restrict__ data, const float* __restrict__ query,
    const int* __restrict__ oidx, const float* __restrict__ norm_data,
    const float* __restrict__ projq, const float* __restrict__ projs,
    float* __restrict__ out)
{
    const int b2 = blockIdx.x, b = b2 >> 1, half = b2 & 1;
    const int t = threadIdx.x, lane = t & 63, w = t >> 6, h = b >> 7;
    __shared__ float ipPart[32 * 4];
    int u[cK]; int U = 0;
    for (int k = 0; k < cK; ++k) {
        int v = oidx[b * cK + k];
        bool dup = false;
        for (int j = 0; j < U; ++j) dup = dup || (u[j] == v);
        if (!dup) u[U++] = v;
    }
    for (int i = 1; i < U; ++i) {
        int key = u[i], j = i - 1;
        while (j >= 0 && u[j] > key) { u[j + 1] = u[j]; --j; }
        u[j + 1] = key;
    }
    unsigned long long m0 = 0, m1 = 0;
    for (int k = 0; k < U; ++k) {
        int v = u[k];
        if (v < 64) m0 |= 1ull << v; else m1 |= 1ull << (v - 64);
    }
    int ui[cK]; float prO[cK];
    #pragma unroll
    for (int k = 0; k < cK; ++k) ui[k] = (k < U) ? u[k] : 0;
    #pragma unroll
    for (int k = 0; k < cK; ++k) prO[k] = (k < U) ? projq[t * cD + ui[k]] : 0.0f;
    float qv = 0.0f;
    for (int d = 0; d < cD; ++d)
        qv = fmaf(query[h * cD + d], projs[d * cS + t], qv);
    const float* __restrict__ chunk = data + (size_t)b * (cN * cD) + half * (32 * cD);
    float acc[32];
    #pragma unroll
    for (int n = 0; n < 32; ++n) acc[n] = 0.0f;
    for (int dc = 0; dc < cD / 16; ++dc) {
        float pm[16];
        const float4* p4 = reinterpret_cast<const float4*>(projq + t * cD + dc * 16);
        #pragma unroll
        for (int j = 0; j < 4; ++j) {
            float4 v = p4[j];
            float tmp[4] = { v.x, v.y, v.z, v.w };
            #pragma unroll
            for (int e = 0; e < 4; ++e) {
                int d = dc * 16 + j * 4 + e;
                bool msk = (((d < 64) ? (m0 >> d) : (m1 >> (d - 64))) & 1ull) != 0;
                pm[j * 4 + e] = msk ? 0.0f : tmp[e];
            }
        }
        #pragma unroll
        for (int n = 0; n < 32; ++n) {
            const float* __restrict__ r = chunk + n * cD + dc * 16;
            #pragma unroll
            for (int i = 0; i < 16; ++i)
                acc[n] = fmaf(r[i], pm[i], acc[n]);
        }
    }
    #pragma unroll
    for (int n = 0; n < 32; ++n) {
        const int nn = half * 32 + n;
        const float* __restrict__ r = chunk + n * cD;
        float o = 0.0f;
        #pragma unroll
        for (int k = 0; k < cK; ++k)
            o = fmaf((k < U) ? r[ui[k]] : 0.0f, prO[k], o);
        const bool bitIn = acc[n] > 0.0f;
        unsigned long long mIn = __ballot(bitIn);
        unsigned long long mOut = __ballot(o > 0.0f);
        float v = bitIn ? qv : -qv;
        #pragma unroll
        for (int off = 32; off > 0; off >>= 1) v += __shfl_down(v, off);
        if (lane == 0) ipPart[n * 4 + w] = v;
        if (lane < 8) {
            out[(size_t)b * (cN * 32) + nn * 32 + w * 8 + lane] =
                (float)((mIn >> (8 * lane)) & 0xFFull);
            if (w < 2)
                out[HASH_OUT_BASE + (size_t)b * (cN * 16) + nn * 16 + w * 8 + lane] =
                    (float)((mOut >> (8 * lane)) & 0xFFull);
        }
    }
    __syncthreads();
    if (t < 32) {
        float ip = ipPart[t * 4 + 0] + ipPart[t * 4 + 1] + ipPart[t * 4 + 2] + ipPart[t * 4 + 3];
        out[SCORE_BASE + b * cN + half * 32 + t] = 0.0048957583f * norm_data[b * cN + half * 32 + t] * ip;
    }
}

extern "C" void kernel_launch(void* const* d_in, const int* in_sizes, int n_in,
                              void* d_out, int out_size, void* d_ws, size_t ws_size,
                              hipStream_t stream) {
    const float* data      = (const float*)d_in[0];
    const float* query     = (const float*)d_in[1];
    const int*   oidx      = (const int*)d_in[2];
    const float* norm_data = (const float*)d_in[3];
    // d_in[4] = norm_outlier: unused by the reference
    const float* projq     = (const float*)d_in[5];  // proj_dir_quant [S,D]
    const float* projs     = (const float*)d_in[6];  // proj_dir_score [D,S]
    float* out = (float*)d_out;

    if (ws_size >= WS_NEED) {
        float* qv  = (float*)d_ws;
        short* bhi = (short*)((char*)d_ws + WS_BHI);
        short* blo = (short*)((char*)d_ws + WS_BLO);
        qjl_qv<<<cH, cS, 0, stream>>>(query, projs, qv);
        qjl_bfrag<<<16, 256, 0, stream>>>(projq, bhi, blo);
        qjl_mfma<<<cH * cG, 256, 0, stream>>>(data, oidx, norm_data, projq,
                                              qv, bhi, blo, out);
    } else {
        qjl_valu<<<cH * cG * 2, 256, 0, stream>>>(data, query, oidx, norm_data,
                                                  projq, projs, out);
    }
}

// Round 19
// 193.603 us; speedup vs baseline: 2.3874x; 2.3874x over previous
//
#include <hip/hip_runtime.h>
#include <hip/hip_bf16.h>

// QJLSketch: H=32, G=128, N=64, D=128, S=256, K=8
// d_out (float32, concatenated):
//   [0,        8388608): hash_inlier  [32,128,64,32] byte values as floats
//   [8388608, 12582912): hash_outlier [32,128,64,16] byte values as floats
//   [12582912,12845056): scores       [32, 128*64]
//
// Strategy: bf16 hi/lo split MFMA GEMM (fast approx) + exact f32-chain fixup for
// |value| < EPS. Non-flagged signs provably match the reference's sequential
// f32 FMA chain; flagged ones recomputed with the verified chain semantics.
// R19: AGPR reduction via DECOMPOSITION (not launch_bounds coercion, which
// spilled in R10/R13/R14/R18): each chunk split into two 32-row blocks
// (grid 8192). acc[8] = 32 AGPR -> live state ~84 VGPR + 32 AGPR = 116 <= 128
// -> HW can schedule 4 waves/SIMD under the safe (256,3) promise.
// LDS 21.5KB. Per-block setup (sort/pO) duplicated across halves - cheap.

typedef __attribute__((ext_vector_type(8))) short short8;
typedef __attribute__((ext_vector_type(4))) float f32x4;

constexpr int cH = 32, cG = 128, cN = 64, cD = 128, cS = 256, cK = 8;
constexpr int HASH_OUT_BASE = cH * cG * cN * (cS / 8);                  // 8388608
constexpr int SCORE_BASE    = HASH_OUT_BASE + cH * cG * cN * (cS / 16); // 12582912
constexpr float EPS_IN  = 1e-3f;
constexpr float EPS_OUT = 1e-3f;
constexpr size_t WS_BHI = 32768, WS_BLO = 98304, WS_NEED = 163840;

#define MFMA(a, b, c) __builtin_amdgcn_mfma_f32_16x16x32_bf16(a, b, c, 0, 0, 0)

// Integer RNE f32->bf16 (valid for all finite x; data is N(0,1), no NaN/Inf).
__device__ inline short f2bf(float x) {
    unsigned u = __builtin_bit_cast(unsigned, x);
    u += 0x7FFFu + ((u >> 16) & 1u);
    return (short)(u >> 16);
}
__device__ inline float bf2f(short s) {
    return __builtin_bit_cast(float, (unsigned)((unsigned short)s) << 16);
}
__device__ inline unsigned long long sel4(unsigned long long a0, unsigned long long a1,
                                          unsigned long long a2, unsigned long long a3, int r) {
    unsigned long long x = a0;
    x = (r == 1) ? a1 : x; x = (r == 2) ? a2 : x; x = (r == 3) ? a3 : x;
    return x;
}
__device__ inline int sel8(const int* u, int k) {
    int x = u[0];
    x = (k == 1) ? u[1] : x; x = (k == 2) ? u[2] : x; x = (k == 3) ? u[3] : x;
    x = (k == 4) ? u[4] : x; x = (k == 5) ? u[5] : x; x = (k == 6) ? u[6] : x;
    x = (k == 7) ? u[7] : x;
    return x;
}
#define CE(i, j) { int a = u[i], b = u[j]; u[i] = min(a, b); u[j] = max(a, b); }

#define SORT8_AND_MASK(oidx_ptr, bb)                                   \
    int u[cK];                                                         \
    _Pragma("unroll")                                                  \
    for (int k = 0; k < cK; ++k) u[k] = (oidx_ptr)[(bb) * cK + k];     \
    unsigned long long m0 = 0, m1 = 0;                                 \
    _Pragma("unroll")                                                  \
    for (int k = 0; k < cK; ++k) {                                     \
        int v = u[k];                                                  \
        if (v < 64) m0 |= 1ull << v; else m1 |= 1ull << (v - 64);      \
    }                                                                  \
    CE(0,1) CE(2,3) CE(4,5) CE(6,7)                                    \
    CE(0,2) CE(1,3) CE(4,6) CE(5,7)                                    \
    CE(1,2) CE(5,6)                                                    \
    CE(0,4) CE(1,5) CE(2,6) CE(3,7)                                    \
    CE(2,4) CE(3,5)                                                    \
    CE(1,2) CE(3,4) CE(5,6)

// Exact reference chain for one (row,s) inlier value (rare). Vectorized.
__device__ __attribute__((noinline)) float exact_inlier(
    const float* __restrict__ dr, const float* __restrict__ pr,
    unsigned long long m0, unsigned long long m1)
{
    float ex = 0.0f;
    #pragma unroll 1
    for (int dc = 0; dc < 4; ++dc) {
        float4 da[8], pa[8];
        #pragma unroll
        for (int j = 0; j < 8; ++j) {
            da[j] = reinterpret_cast<const float4*>(dr)[dc * 8 + j];
            pa[j] = reinterpret_cast<const float4*>(pr)[dc * 8 + j];
        }
        #pragma unroll
        for (int j = 0; j < 8; ++j) {
            float dv[4] = { da[j].x, da[j].y, da[j].z, da[j].w };
            float pv[4] = { pa[j].x, pa[j].y, pa[j].z, pa[j].w };
            #pragma unroll
            for (int e = 0; e < 4; ++e) {
                const int d = dc * 32 + j * 4 + e;
                const bool msk = ((((d < 64) ? (m0 >> d) : (m1 >> (d - 64))) & 1ull) != 0);
                ex = fmaf(dv[e], msk ? 0.0f : pv[e], ex);
            }
        }
    }
    return ex;
}

// --- precompute: sketched_q[h][s] (sequential chain; scores have 2% tol) ---
__global__ __launch_bounds__(256) void qjl_qv(
    const float* __restrict__ query, const float* __restrict__ projs,
    float* __restrict__ qv_out)
{
    const int h = blockIdx.x, s = threadIdx.x;
    float qa = 0.0f;
    for (int d = 0; d < cD; ++d)
        qa = fmaf(query[h * cD + d], projs[d * cS + s], qa);
    qv_out[h * cS + s] = qa;
}

// --- precompute: B fragments (projq hi/lo bf16) in MFMA lane order ---
__global__ __launch_bounds__(256) void qjl_bfrag(
    const float* __restrict__ projq, short* __restrict__ bhi, short* __restrict__ blo)
{
    const int idx = blockIdx.x * 256 + threadIdx.x;    // [0, 4096)
    const int l = idx & 63, nt = (idx >> 6) & 15, ksub = idx >> 10;
    const int s = nt * 16 + (l & 15);
    const int k0 = ksub * 32 + (l >> 4) * 8;
    #pragma unroll
    for (int j = 0; j < 8; ++j) {
        float x = projq[s * cD + k0 + j];
        short h = f2bf(x);
        bhi[idx * 8 + j] = h;
        blo[idx * 8 + j] = f2bf(x - bf2f(h));
    }
}

__global__ __launch_bounds__(256, 3) void qjl_mfma(
    const float* __restrict__ data, const int* __restrict__ oidx,
    const float* __restrict__ norm_data, const float* __restrict__ projq,
    const float* __restrict__ qv_ws, const short* __restrict__ bhi_ws,
    const short* __restrict__ blo_ws, float* __restrict__ out)
{
    const int b2   = blockIdx.x;      // 0..8191
    const int b    = b2 >> 1;         // h*G + g
    const int half = b2 & 1;          // 32-row half of the chunk
    const int t    = threadIdx.x;
    const int lane = t & 63;
    const int w    = t >> 6;          // wave owns nt = 4w..4w+3 (s in [64w, 64w+64))
    const int c0   = lane & 15;
    const int g16  = lane >> 4;
    const int h    = b >> 7;
    const int rowbase = half * 32;

    __shared__ short A_hi[8 * 64 * 8];      // 8 KB   [(ksub*2+mt)*64+l]*8  (MASKED data)
    __shared__ short A_lo[8 * 64 * 8];      // 8 KB
    __shared__ float dO[cK * 32];           // 1 KB   [k][row_local]
    __shared__ float pO[cK * 128];          // 4 KB   [k][s<128] (outlier path only)
    __shared__ float ipPart[32 * 4];        // 0.5 KB [row_local][wave]
    // total 21.5 KB

    const f32x4 zero4 = { 0.f, 0.f, 0.f, 0.f };

    SORT8_AND_MASK(oidx, b)
    const float* __restrict__ chunk = data + (size_t)b * (cN * cD);

    // --- stage A (masked, hi/lo) in fragment slot order: 2 slots/thread ---
    #pragma unroll
    for (int i = 0; i < 2; ++i) {
        const int slot = i * 256 + t;       // 512 slots of 16B
        const int l = slot & 63, frag = slot >> 6;      // frag = ksub*2 + mt
        const int mt = frag & 1, ksub = frag >> 1;
        const int row = rowbase + mt * 16 + (l & 15);
        const int k0 = ksub * 32 + (l >> 4) * 8;
        const float4* p = reinterpret_cast<const float4*>(chunk + row * cD + k0);
        float4 v0 = p[0], v1 = p[1];
        float xs[8] = { v0.x, v0.y, v0.z, v0.w, v1.x, v1.y, v1.z, v1.w };
        const unsigned bits = (unsigned)(((k0 < 64) ? (m0 >> k0) : (m1 >> (k0 - 64))) & 0xFFull);
        short hs[8], ls[8];
        #pragma unroll
        for (int e = 0; e < 8; ++e) {
            float x = ((bits >> e) & 1u) ? 0.0f : xs[e];   // key_inlier = data*(1-mask)
            hs[e] = f2bf(x);
            ls[e] = f2bf(x - bf2f(hs[e]));
        }
        *reinterpret_cast<short8*>(&A_hi[slot * 8]) =
            short8{ hs[0], hs[1], hs[2], hs[3], hs[4], hs[5], hs[6], hs[7] };
        *reinterpret_cast<short8*>(&A_lo[slot * 8]) =
            short8{ ls[0], ls[1], ls[2], ls[3], ls[4], ls[5], ls[6], ls[7] };
    }
    // --- stage dO[k][row_local] (256 elems, 1/thread) ---
    {
        const int k = t >> 5, row = t & 31;
        dO[t] = chunk[(rowbase + row) * cD + sel8(u, k)];
    }
    // --- stage pO[k][s<128] (1024 elems, 4/thread; dup slots -> 0) ---
    #pragma unroll
    for (int i = 0; i < 4; ++i) {
        const int idx = i * 256 + t;
        const int k = idx >> 7, s = idx & 127;
        const int uk = sel8(u, k);
        const bool dup = (k > 0) && (uk == sel8(u, k - 1));
        float x = projq[s * cD + uk];
        pO[idx] = dup ? 0.0f : x;
    }
    __syncthreads();

    // --- outlier path: only waves 0,1 (s < 128) ---
    if (w < 2) {
        short8 aO[2];
        #pragma unroll
        for (int mt = 0; mt < 2; ++mt) {
            short v8[8];
            #pragma unroll
            for (int k = 0; k < cK; ++k) {
                float x = dO[k * 32 + mt * 16 + c0];
                short hi = f2bf(x), lo = f2bf(x - bf2f(hi));
                v8[k] = (g16 == 2) ? lo : ((g16 == 3) ? (short)0 : hi);
            }
            aO[mt] = short8{ v8[0], v8[1], v8[2], v8[3], v8[4], v8[5], v8[6], v8[7] };
        }
        #pragma unroll
        for (int q = 0; q < 4; ++q) {
            const int s = (w * 4 + q) * 16 + c0;
            short v8[8];
            #pragma unroll
            for (int k = 0; k < cK; ++k) {
                float x = pO[k * 128 + s];
                short hi = f2bf(x), lo = f2bf(x - bf2f(hi));
                v8[k] = (g16 == 1) ? lo : ((g16 == 3) ? (short)0 : hi);
            }
            short8 bO = short8{ v8[0], v8[1], v8[2], v8[3], v8[4], v8[5], v8[6], v8[7] };
            #pragma unroll
            for (int mt = 0; mt < 2; ++mt) {
                f32x4 accO = MFMA(aO[mt], bO, zero4);
                unsigned long long b0, b1, b2, b3;
                #pragma unroll
                for (int r = 0; r < 4; ++r) {
                    float v = accO[r];
                    if (fabsf(v) < EPS_OUT) {
                        int rl = mt * 16 + 4 * g16 + r;
                        float o = 0.0f;
                        #pragma unroll
                        for (int k = 0; k < cK; ++k)
                            o = fmaf(dO[k * 32 + rl], pO[k * 128 + s], o);
                        v = o;
                    }
                    unsigned long long bal = __ballot(v > 0.0f);
                    if (r == 0) b0 = bal; else if (r == 1) b1 = bal;
                    else if (r == 2) b2 = bal; else b3 = bal;
                }
                if (lane < 32) {
                    int r = lane & 3, g = (lane >> 2) & 3, hb = lane >> 4;
                    unsigned long long bb = sel4(b0, b1, b2, b3, r);
                    int row = rowbase + mt * 16 + 4 * g + r;
                    out[HASH_OUT_BASE + (size_t)b * (cN * 16) + row * 16 + (w * 4 + q) * 2 + hb] =
                        (float)((bb >> (16 * g + 8 * hb)) & 0xFFull);
                }
            }
        }
    }

    // --- inlier GEMM: sk_in directly (A masked). K'=384: hi*Bhi, hi*Blo, lo*Bhi ---
    f32x4 acc[8];
    #pragma unroll
    for (int i = 0; i < 8; ++i)
        acc[i] = zero4;

    #pragma unroll
    for (int ksub = 0; ksub < 4; ++ksub) {
        short8 ah[2], al[2];
        #pragma unroll
        for (int mt = 0; mt < 2; ++mt) {
            ah[mt] = *reinterpret_cast<const short8*>(&A_hi[((ksub * 2 + mt) * 64 + lane) * 8]);
            al[mt] = *reinterpret_cast<const short8*>(&A_lo[((ksub * 2 + mt) * 64 + lane) * 8]);
        }
        #pragma unroll
        for (int q = 0; q < 4; ++q) {
            short8 bh = *reinterpret_cast<const short8*>(
                &bhi_ws[((ksub * 16 + w * 4 + q) * 64 + lane) * 8]);
            #pragma unroll
            for (int mt = 0; mt < 2; ++mt)
                acc[mt * 4 + q] = MFMA(ah[mt], bh, acc[mt * 4 + q]);
            short8 bl = *reinterpret_cast<const short8*>(
                &blo_ws[((ksub * 16 + w * 4 + q) * 64 + lane) * 8]);
            #pragma unroll
            for (int mt = 0; mt < 2; ++mt)
                acc[mt * 4 + q] = MFMA(ah[mt], bl, acc[mt * 4 + q]);
            #pragma unroll
            for (int mt = 0; mt < 2; ++mt)
                acc[mt * 4 + q] = MFMA(al[mt], bh, acc[mt * 4 + q]);
        }
    }

    // --- hash_inlier + ip partials, vectorized exact-chain fixup ---
    float qvv[4];
    #pragma unroll
    for (int q = 0; q < 4; ++q)
        qvv[q] = qv_ws[h * cS + (w * 4 + q) * 16 + c0];

    #pragma unroll
    for (int mt = 0; mt < 2; ++mt) {
        float part[4] = { 0.f, 0.f, 0.f, 0.f };
        #pragma unroll
        for (int q = 0; q < 4; ++q) {
            unsigned long long b0, b1, b2, b3;
            #pragma unroll
            for (int r = 0; r < 4; ++r) {
                float v = acc[mt * 4 + q][r];
                if (fabsf(v) < EPS_IN) {
                    int row = rowbase + mt * 16 + 4 * g16 + r;
                    int s = (w * 4 + q) * 16 + c0;
                    v = exact_inlier(chunk + row * cD, projq + s * cD, m0, m1);
                }
                bool bit = v > 0.0f;
                unsigned long long bal = __ballot(bit);
                part[r] += bit ? qvv[q] : -qvv[q];
                if (r == 0) b0 = bal; else if (r == 1) b1 = bal;
                else if (r == 2) b2 = bal; else b3 = bal;
            }
            if (lane < 32) {
                int r = lane & 3, g = (lane >> 2) & 3, hb = lane >> 4;
                unsigned long long bb = sel4(b0, b1, b2, b3, r);
                int row = rowbase + mt * 16 + 4 * g + r;
                out[(size_t)b * (cN * 32) + row * 32 + (w * 4 + q) * 2 + hb] =
                    (float)((bb >> (16 * g + 8 * hb)) & 0xFFull);
            }
        }
        #pragma unroll
        for (int r = 0; r < 4; ++r) {
            float x = part[r];
            x += __shfl_xor(x, 1); x += __shfl_xor(x, 2);
            x += __shfl_xor(x, 4); x += __shfl_xor(x, 8);
            if (c0 == 0) ipPart[(mt * 16 + 4 * g16 + r) * 4 + w] = x;
        }
    }
    __syncthreads();
    if (t < 32) {
        float ip = ipPart[t * 4 + 0] + ipPart[t * 4 + 1]
                 + ipPart[t * 4 + 2] + ipPart[t * 4 + 3];
        const float scl = 0.0048957583f;   // sqrt(pi/2)/256
        out[SCORE_BASE + (size_t)b * cN + rowbase + t] =
            scl * norm_data[b * cN + rowbase + t] * ip;
    }
}

// ---------------- fallback (R3 kernel, passed): used if ws too small ----------------
__global__ __launch_bounds__(256) void qjl_valu(
    const float* __restrict__ data, const float* __restrict__ query,
    const int* __restrict__ oidx, const float* __restrict__ norm_data,
    const float* __restrict__ projq, const float* __restrict__ projs,
    float* __restrict__ out)
{
    const int b2 = blockIdx.x, b = b2 >> 1, half = b2 & 1;
    const int t = threadIdx.x, lane = t & 63, w = t >> 6, h = b >> 7;
    __shared__ float ipPart[32 * 4];
    int u[cK]; int U = 0;
    for (int k = 0; k < cK; ++k) {
        int v = oidx[b * cK + k];
        bool dup = false;
        for (int j = 0; j < U; ++j) dup = dup || (u[j] == v);
        if (!dup) u[U++] = v;
    }
    for (int i = 1; i < U; ++i) {
        int key = u[i], j = i - 1;
        while (j >= 0 && u[j] > key) { u[j + 1] = u[j]; --j; }
        u[j + 1] = key;
    }
    unsigned long long m0 = 0, m1 = 0;
    for (int k = 0; k < U; ++k) {
        int v = u[k];
        if (v < 64) m0 |= 1ull << v; else m1 |= 1ull << (v - 64);
    }
    int ui[cK]; float prO[cK];
    #pragma unroll
    for (int k = 0; k < cK; ++k) ui[k] = (k < U) ? u[k] : 0;
    #pragma unroll
    for (int k = 0; k < cK; ++k) prO[k] = (k < U) ? projq[t * cD + ui[k]] : 0.0f;
    float qv = 0.0f;
    for (int d = 0; d < cD; ++d)
        qv = fmaf(query[h * cD + d], projs[d * cS + t], qv);
    const float* __restrict__ chunk = data + (size_t)b * (cN * cD) + half * (32 * cD);
    float acc[32];
    #pragma unroll
    for (int n = 0; n < 32; ++n) acc[n] = 0.0f;
    for (int dc = 0; dc < cD / 16; ++dc) {
        float pm[16];
        const float4* p4 = reinterpret_cast<const float4*>(projq + t * cD + dc * 16);
        #pragma unroll
        for (int j = 0; j < 4; ++j) {
            float4 v = p4[j];
            float tmp[4] = { v.x, v.y, v.z, v.w };
            #pragma unroll
            for (int e = 0; e < 4; ++e) {
                int d = dc * 16 + j * 4 + e;
                bool msk = (((d < 64) ? (m0 >> d) : (m1 >> (d - 64))) & 1ull) != 0;
                pm[j * 4 + e] = msk ? 0.0f : tmp[e];
            }
        }
        #pragma unroll
        for (int n = 0; n < 32; ++n) {
            const float* __restrict__ r = chunk + n * cD + dc * 16;
            #pragma unroll
            for (int i = 0; i < 16; ++i)
                acc[n] = fmaf(r[i], pm[i], acc[n]);
        }
    }
    #pragma unroll
    for (int n = 0; n < 32; ++n) {
        const int nn = half * 32 + n;
        const float* __restrict__ r = chunk + n * cD;
        float o = 0.0f;
        #pragma unroll
        for (int k = 0; k < cK; ++k)
            o = fmaf((k < U) ? r[ui[k]] : 0.0f, prO[k], o);
        const bool bitIn = acc[n] > 0.0f;
        unsigned long long mIn = __ballot(bitIn);
        unsigned long long mOut = __ballot(o > 0.0f);
        float v = bitIn ? qv : -qv;
        #pragma unroll
        for (int off = 32; off > 0; off >>= 1) v += __shfl_down(v, off);
        if (lane == 0) ipPart[n * 4 + w] = v;
        if (lane < 8) {
            out[(size_t)b * (cN * 32) + nn * 32 + w * 8 + lane] =
                (float)((mIn >> (8 * lane)) & 0xFFull);
            if (w < 2)
                out[HASH_OUT_BASE + (size_t)b * (cN * 16) + nn * 16 + w * 8 + lane] =
                    (float)((mOut >> (8 * lane)) & 0xFFull);
        }
    }
    __syncthreads();
    if (t < 32) {
        float ip = ipPart[t * 4 + 0] + ipPart[t * 4 + 1] + ipPart[t * 4 + 2] + ipPart[t * 4 + 3];
        out[SCORE_BASE + b * cN + half * 32 + t] = 0.0048957583f * norm_data[b * cN + half * 32 + t] * ip;
    }
}

extern "C" void kernel_launch(void* const* d_in, const int* in_sizes, int n_in,
                              void* d_out, int out_size, void* d_ws, size_t ws_size,
                              hipStream_t stream) {
    const float* data      = (const float*)d_in[0];
    const float* query     = (const float*)d_in[1];
    const int*   oidx      = (const int*)d_in[2];
    const float* norm_data = (const float*)d_in[3];
    // d_in[4] = norm_outlier: unused by the reference
    const float* projq     = (const float*)d_in[5];  // proj_dir_quant [S,D]
    const float* projs     = (const float*)d_in[6];  // proj_dir_score [D,S]
    float* out = (float*)d_out;

    if (ws_size >= WS_NEED) {
        float* qv  = (float*)d_ws;
        short* bhi = (short*)((char*)d_ws + WS_BHI);
        short* blo = (short*)((char*)d_ws + WS_BLO);
        qjl_qv<<<cH, cS, 0, stream>>>(query, projs, qv);
        qjl_bfrag<<<16, 256, 0, stream>>>(projq, bhi, blo);
        qjl_mfma<<<cH * cG * 2, 256, 0, stream>>>(data, oidx, norm_data, projq,
                                                  qv, bhi, blo, out);
    } else {
        qjl_valu<<<cH * cG * 2, 256, 0, stream>>>(data, query, oidx, norm_data,
                                                  projq, projs, out);
    }
}

// Round 20
// 160.776 us; speedup vs baseline: 2.8748x; 1.2042x over previous
//
#include <hip/hip_runtime.h>
#include <hip/hip_bf16.h>

// QJLSketch: H=32, G=128, N=64, D=128, S=256, K=8
// d_out (float32, concatenated):
//   [0,        8388608): hash_inlier  [32,128,64,32] byte values as floats
//   [8388608, 12582912): hash_outlier [32,128,64,16] byte values as floats
//   [12582912,12845056): scores       [32, 128*64]
//
// Strategy: bf16 hi/lo split MFMA GEMM (fast approx) + exact f32-chain fixup for
// |value| < EPS. Non-flagged signs provably match the reference's sequential
// f32 FMA chain; flagged ones recomputed with the verified chain semantics.
// R20 = R17 (champion, 167us) with TRUNCATION hi/lo split (no RNE needed --
// correctness rests on |approx-exact| < EPS, and trunc split bound is
// ~1e-4 << EPS=1e-3). ~4-5 VALU/elem vs ~11 for integer-RNE: the A conversion
// was ~75us of per-SIMD VALU issue (the dominant identified cost at
// VALUBusy 41%). Pair-packed into dwords; layouts bit-compatible.

typedef __attribute__((ext_vector_type(8))) short short8;
typedef __attribute__((ext_vector_type(4))) float f32x4;

constexpr int cH = 32, cG = 128, cN = 64, cD = 128, cS = 256, cK = 8;
constexpr int HASH_OUT_BASE = cH * cG * cN * (cS / 8);                  // 8388608
constexpr int SCORE_BASE    = HASH_OUT_BASE + cH * cG * cN * (cS / 16); // 12582912
constexpr float EPS_IN  = 1e-3f;
constexpr float EPS_OUT = 1e-3f;
constexpr size_t WS_BHI = 32768, WS_BLO = 98304, WS_NEED = 163840;

#define MFMA(a, b, c) __builtin_amdgcn_mfma_f32_16x16x32_bf16(a, b, c, 0, 0, 0)

// Truncation hi/lo split of a pair of f32 into packed bf16 dwords.
// hi = top16(x) (exact residual r = x - hi), lo = top16(r).
// |x - (hi+lo)| <= 2^-16 |x|  -- well inside the EPS fixup margin.
__device__ inline void split_pair(float x0, float x1, unsigned& hpk, unsigned& lpk) {
    unsigned u0 = __builtin_bit_cast(unsigned, x0);
    unsigned u1 = __builtin_bit_cast(unsigned, x1);
    unsigned h1 = u1 & 0xFFFF0000u;
    float hf0 = __builtin_bit_cast(float, u0 & 0xFFFF0000u);
    float hf1 = __builtin_bit_cast(float, h1);
    unsigned r0 = __builtin_bit_cast(unsigned, x0 - hf0);
    unsigned r1 = __builtin_bit_cast(unsigned, x1 - hf1);
    hpk = (u0 >> 16) | h1;
    lpk = (r0 >> 16) | (r1 & 0xFFFF0000u);
}

__device__ inline unsigned long long sel4(unsigned long long a0, unsigned long long a1,
                                          unsigned long long a2, unsigned long long a3, int r) {
    unsigned long long x = a0;
    x = (r == 1) ? a1 : x; x = (r == 2) ? a2 : x; x = (r == 3) ? a3 : x;
    return x;
}
__device__ inline int sel8(const int* u, int k) {
    int x = u[0];
    x = (k == 1) ? u[1] : x; x = (k == 2) ? u[2] : x; x = (k == 3) ? u[3] : x;
    x = (k == 4) ? u[4] : x; x = (k == 5) ? u[5] : x; x = (k == 6) ? u[6] : x;
    x = (k == 7) ? u[7] : x;
    return x;
}
#define CE(i, j) { int a = u[i], b = u[j]; u[i] = min(a, b); u[j] = max(a, b); }

#define SORT8_AND_MASK(oidx_ptr, bb)                                   \
    int u[cK];                                                         \
    _Pragma("unroll")                                                  \
    for (int k = 0; k < cK; ++k) u[k] = (oidx_ptr)[(bb) * cK + k];     \
    unsigned long long m0 = 0, m1 = 0;                                 \
    _Pragma("unroll")                                                  \
    for (int k = 0; k < cK; ++k) {                                     \
        int v = u[k];                                                  \
        if (v < 64) m0 |= 1ull << v; else m1 |= 1ull << (v - 64);      \
    }                                                                  \
    CE(0,1) CE(2,3) CE(4,5) CE(6,7)                                    \
    CE(0,2) CE(1,3) CE(4,6) CE(5,7)                                    \
    CE(1,2) CE(5,6)                                                    \
    CE(0,4) CE(1,5) CE(2,6) CE(3,7)                                    \
    CE(2,4) CE(3,5)                                                    \
    CE(1,2) CE(3,4) CE(5,6)

// Exact reference chain for one (row,s) inlier value (rare). Vectorized.
__device__ __attribute__((noinline)) float exact_inlier(
    const float* __restrict__ dr, const float* __restrict__ pr,
    unsigned long long m0, unsigned long long m1)
{
    float ex = 0.0f;
    #pragma unroll 1
    for (int dc = 0; dc < 4; ++dc) {
        float4 da[8], pa[8];
        #pragma unroll
        for (int j = 0; j < 8; ++j) {
            da[j] = reinterpret_cast<const float4*>(dr)[dc * 8 + j];
            pa[j] = reinterpret_cast<const float4*>(pr)[dc * 8 + j];
        }
        #pragma unroll
        for (int j = 0; j < 8; ++j) {
            float dv[4] = { da[j].x, da[j].y, da[j].z, da[j].w };
            float pv[4] = { pa[j].x, pa[j].y, pa[j].z, pa[j].w };
            #pragma unroll
            for (int e = 0; e < 4; ++e) {
                const int d = dc * 32 + j * 4 + e;
                const bool msk = ((((d < 64) ? (m0 >> d) : (m1 >> (d - 64))) & 1ull) != 0);
                ex = fmaf(dv[e], msk ? 0.0f : pv[e], ex);
            }
        }
    }
    return ex;
}

// --- precompute: sketched_q[h][s] (sequential chain; scores have 2% tol) ---
__global__ __launch_bounds__(256) void qjl_qv(
    const float* __restrict__ query, const float* __restrict__ projs,
    float* __restrict__ qv_out)
{
    const int h = blockIdx.x, s = threadIdx.x;
    float qa = 0.0f;
    for (int d = 0; d < cD; ++d)
        qa = fmaf(query[h * cD + d], projs[d * cS + s], qa);
    qv_out[h * cS + s] = qa;
}

// --- precompute: B fragments (projq hi/lo bf16, truncation split) ---
__global__ __launch_bounds__(256) void qjl_bfrag(
    const float* __restrict__ projq, short* __restrict__ bhi, short* __restrict__ blo)
{
    const int idx = blockIdx.x * 256 + threadIdx.x;    // [0, 4096)
    const int l = idx & 63, nt = (idx >> 6) & 15, ksub = idx >> 10;
    const int s = nt * 16 + (l & 15);
    const int k0 = ksub * 32 + (l >> 4) * 8;
    unsigned* bh32 = reinterpret_cast<unsigned*>(bhi);
    unsigned* bl32 = reinterpret_cast<unsigned*>(blo);
    #pragma unroll
    for (int e = 0; e < 4; ++e) {
        float x0 = projq[s * cD + k0 + 2 * e];
        float x1 = projq[s * cD + k0 + 2 * e + 1];
        unsigned hp, lp;
        split_pair(x0, x1, hp, lp);
        bh32[idx * 4 + e] = hp;
        bl32[idx * 4 + e] = lp;
    }
}

__global__ __launch_bounds__(256, 3) void qjl_mfma(
    const float* __restrict__ data, const int* __restrict__ oidx,
    const float* __restrict__ norm_data, const float* __restrict__ projq,
    const float* __restrict__ qv_ws, const short* __restrict__ bhi_ws,
    const short* __restrict__ blo_ws, float* __restrict__ out)
{
    const int b    = blockIdx.x;      // h*G + g
    const int t    = threadIdx.x;
    const int lane = t & 63;
    const int w    = t >> 6;          // wave owns nt = 4w..4w+3 (s in [64w, 64w+64))
    const int c0   = lane & 15;
    const int g16  = lane >> 4;
    const int h    = b >> 7;

    __shared__ char  A_buf[32768];          // 32 KB: A_hi/A_lo, then hash staging
    __shared__ float dO[cK * cN];           // 2 KB   [k][row]
    __shared__ float pO[cK * 128];          // 4 KB   [k][s<128]
    __shared__ float ipPart[cN * 4];        // 1 KB
    short* A_hi  = reinterpret_cast<short*>(A_buf);
    short* A_lo  = reinterpret_cast<short*>(A_buf + 16384);
    float* hashI = reinterpret_cast<float*>(A_buf);            // [64][33] = 8448 B
    float* hashO = reinterpret_cast<float*>(A_buf + 16384);    // [64][17] = 4352 B

    const f32x4 zero4 = { 0.f, 0.f, 0.f, 0.f };

    SORT8_AND_MASK(oidx, b)
    const float* __restrict__ chunk = data + (size_t)b * (cN * cD);

    // --- stage A (masked, hi/lo trunc-split) in fragment slot order ---
    #pragma unroll
    for (int i = 0; i < 4; ++i) {
        const int slot = i * 256 + t;
        const int l = slot & 63, frag = slot >> 6;
        const int mt = frag & 3, ksub = frag >> 2;
        const int row = mt * 16 + (l & 15);
        const int k0 = ksub * 32 + (l >> 4) * 8;
        const float4* p = reinterpret_cast<const float4*>(chunk + row * cD + k0);
        float4 v0 = p[0], v1 = p[1];
        float xs[8] = { v0.x, v0.y, v0.z, v0.w, v1.x, v1.y, v1.z, v1.w };
        const unsigned bits = (unsigned)(((k0 < 64) ? (m0 >> k0) : (m1 >> (k0 - 64))) & 0xFFull);
        unsigned hp[4], lp[4];
        #pragma unroll
        for (int e = 0; e < 4; ++e) {
            float x0 = ((bits >> (2 * e)) & 1u) ? 0.0f : xs[2 * e];
            float x1 = ((bits >> (2 * e + 1)) & 1u) ? 0.0f : xs[2 * e + 1];
            split_pair(x0, x1, hp[e], lp[e]);
        }
        *reinterpret_cast<uint4*>(&A_hi[slot * 8]) = uint4{ hp[0], hp[1], hp[2], hp[3] };
        *reinterpret_cast<uint4*>(&A_lo[slot * 8]) = uint4{ lp[0], lp[1], lp[2], lp[3] };
    }
    // --- stage dO[k][row] (512 elems, 2/thread) ---
    #pragma unroll
    for (int i = 0; i < 2; ++i) {
        const int idx = i * 256 + t;
        const int k = idx >> 6, row = idx & 63;
        dO[idx] = chunk[row * cD + sel8(u, k)];
    }
    // --- stage pO[k][s<128] (1024 elems, 4/thread; dup slots -> 0) ---
    #pragma unroll
    for (int i = 0; i < 4; ++i) {
        const int idx = i * 256 + t;
        const int k = idx >> 7, s = idx & 127;
        const int uk = sel8(u, k);
        const bool dup = (k > 0) && (uk == sel8(u, k - 1));
        float x = projq[s * cD + uk];
        pO[idx] = dup ? 0.0f : x;
    }
    __syncthreads();

    // --- inlier GEMM: sk_in directly (A masked). K'=384: hi*Bhi, hi*Blo, lo*Bhi ---
    f32x4 acc[16];
    #pragma unroll
    for (int i = 0; i < 16; ++i)
        acc[i] = zero4;

    #pragma unroll
    for (int ksub = 0; ksub < 4; ++ksub) {
        short8 ah[4], al[4];
        #pragma unroll
        for (int mt = 0; mt < 4; ++mt) {
            ah[mt] = *reinterpret_cast<const short8*>(&A_hi[((ksub * 4 + mt) * 64 + lane) * 8]);
            al[mt] = *reinterpret_cast<const short8*>(&A_lo[((ksub * 4 + mt) * 64 + lane) * 8]);
        }
        #pragma unroll
        for (int q = 0; q < 4; ++q) {
            short8 bh = *reinterpret_cast<const short8*>(
                &bhi_ws[((ksub * 16 + w * 4 + q) * 64 + lane) * 8]);
            #pragma unroll
            for (int mt = 0; mt < 4; ++mt)
                acc[mt * 4 + q] = MFMA(ah[mt], bh, acc[mt * 4 + q]);
            short8 bl = *reinterpret_cast<const short8*>(
                &blo_ws[((ksub * 16 + w * 4 + q) * 64 + lane) * 8]);
            #pragma unroll
            for (int mt = 0; mt < 4; ++mt)
                acc[mt * 4 + q] = MFMA(ah[mt], bl, acc[mt * 4 + q]);
            #pragma unroll
            for (int mt = 0; mt < 4; ++mt)
                acc[mt * 4 + q] = MFMA(al[mt], bh, acc[mt * 4 + q]);
        }
    }

    __syncthreads();   // all A_hi/A_lo reads done -> A_buf becomes hash staging

    // --- inlier epilogue: fixup + ballots + ip partials; bytes -> hashI LDS ---
    float qvv[4];
    #pragma unroll
    for (int q = 0; q < 4; ++q)
        qvv[q] = qv_ws[h * cS + (w * 4 + q) * 16 + c0];

    #pragma unroll
    for (int mt = 0; mt < 4; ++mt) {
        float part[4] = { 0.f, 0.f, 0.f, 0.f };
        #pragma unroll
        for (int q = 0; q < 4; ++q) {
            unsigned long long b0, b1, b2, b3;
            #pragma unroll
            for (int r = 0; r < 4; ++r) {
                float v = acc[mt * 4 + q][r];
                if (fabsf(v) < EPS_IN) {
                    int row = mt * 16 + 4 * g16 + r;
                    int s = (w * 4 + q) * 16 + c0;
                    v = exact_inlier(chunk + row * cD, projq + s * cD, m0, m1);
                }
                bool bit = v > 0.0f;
                unsigned long long bal = __ballot(bit);
                part[r] += bit ? qvv[q] : -qvv[q];
                if (r == 0) b0 = bal; else if (r == 1) b1 = bal;
                else if (r == 2) b2 = bal; else b3 = bal;
            }
            if (lane < 32) {
                int r = lane & 3, g = (lane >> 2) & 3, hb = lane >> 4;
                unsigned long long bb = sel4(b0, b1, b2, b3, r);
                int row = mt * 16 + 4 * g + r;
                hashI[row * 33 + (w * 4 + q) * 2 + hb] =
                    (float)((bb >> (16 * g + 8 * hb)) & 0xFFull);
            }
        }
        #pragma unroll
        for (int r = 0; r < 4; ++r) {
            float x = part[r];
            x += __shfl_xor(x, 1); x += __shfl_xor(x, 2);
            x += __shfl_xor(x, 4); x += __shfl_xor(x, 8);
            if (c0 == 0) ipPart[(mt * 16 + 4 * g16 + r) * 4 + w] = x;
        }
    }

    // --- outlier phase: ALL 4 waves, ntq = 2w+q (s < 128); bytes -> hashO LDS ---
    {
        short8 aO[4];
        #pragma unroll
        for (int mt = 0; mt < 4; ++mt) {
            unsigned pk[4];
            #pragma unroll
            for (int e = 0; e < 4; ++e) {
                float x0 = dO[(2 * e) * cN + mt * 16 + c0];
                float x1 = dO[(2 * e + 1) * cN + mt * 16 + c0];
                unsigned hp, lp;
                split_pair(x0, x1, hp, lp);
                pk[e] = (g16 == 2) ? lp : ((g16 == 3) ? 0u : hp);
            }
            aO[mt] = __builtin_bit_cast(short8, uint4{ pk[0], pk[1], pk[2], pk[3] });
        }
        #pragma unroll
        for (int q = 0; q < 2; ++q) {
            const int ntq = 2 * w + q;
            const int s = ntq * 16 + c0;
            unsigned pk[4];
            #pragma unroll
            for (int e = 0; e < 4; ++e) {
                float x0 = pO[(2 * e) * 128 + s];
                float x1 = pO[(2 * e + 1) * 128 + s];
                unsigned hp, lp;
                split_pair(x0, x1, hp, lp);
                pk[e] = (g16 == 1) ? lp : ((g16 == 3) ? 0u : hp);
            }
            short8 bO = __builtin_bit_cast(short8, uint4{ pk[0], pk[1], pk[2], pk[3] });
            #pragma unroll
            for (int mt = 0; mt < 4; ++mt) {
                f32x4 accO = MFMA(aO[mt], bO, zero4);
                unsigned long long b0, b1, b2, b3;
                #pragma unroll
                for (int r = 0; r < 4; ++r) {
                    float v = accO[r];
                    if (fabsf(v) < EPS_OUT) {
                        int row = mt * 16 + 4 * g16 + r;
                        float o = 0.0f;
                        #pragma unroll
                        for (int k = 0; k < cK; ++k)
                            o = fmaf(dO[k * cN + row], pO[k * 128 + s], o);
                        v = o;
                    }
                    unsigned long long bal = __ballot(v > 0.0f);
                    if (r == 0) b0 = bal; else if (r == 1) b1 = bal;
                    else if (r == 2) b2 = bal; else b3 = bal;
                }
                if (lane < 32) {
                    int r = lane & 3, g = (lane >> 2) & 3, hb = lane >> 4;
                    unsigned long long bb = sel4(b0, b1, b2, b3, r);
                    int row = mt * 16 + 4 * g + r;
                    hashO[row * 17 + ntq * 2 + hb] =
                        (float)((bb >> (16 * g + 8 * hb)) & 0xFFull);
                }
            }
        }
    }
    __syncthreads();

    // --- coalesced dump: hashI (8/thread), hashO (4/thread), scores ---
    #pragma unroll
    for (int i = 0; i < 2; ++i) {
        const int base = t * 8 + i * 4;            // 4 consecutive, same row
        const int row = base >> 5, col = base & 31;
        float4 v;
        v.x = hashI[row * 33 + col + 0];
        v.y = hashI[row * 33 + col + 1];
        v.z = hashI[row * 33 + col + 2];
        v.w = hashI[row * 33 + col + 3];
        reinterpret_cast<float4*>(out + (size_t)b * (cN * 32))[t * 2 + i] = v;
    }
    {
        const int base = t * 4;                    // 4 consecutive, same row
        const int row = base >> 4, col = base & 15;
        float4 v;
        v.x = hashO[row * 17 + col + 0];
        v.y = hashO[row * 17 + col + 1];
        v.z = hashO[row * 17 + col + 2];
        v.w = hashO[row * 17 + col + 3];
        reinterpret_cast<float4*>(out + HASH_OUT_BASE + (size_t)b * (cN * 16))[t] = v;
    }
    if (t < cN) {
        float ip = ipPart[t * 4 + 0] + ipPart[t * 4 + 1]
                 + ipPart[t * 4 + 2] + ipPart[t * 4 + 3];
        const float scl = 0.0048957583f;   // sqrt(pi/2)/256
        out[SCORE_BASE + (size_t)b * cN + t] = scl * norm_data[b * cN + t] * ip;
    }
}

// ---------------- fallback (R3 kernel, passed): used if ws too small ----------------
__global__ __launch_bounds__(256) void qjl_valu(
    const float* __restrict__ data, const float* __restrict__ query,
    const int* __restrict__ oidx, const float* __restrict__ norm_data,
    const float* __restrict__ projq, const float* __restrict__ projs,
    float* __restrict__ out)
{
    const int b2 = blockIdx.x, b = b2 >> 1, half = b2 & 1;
    const int t = threadIdx.x, lane = t & 63, w = t >> 6, h = b >> 7;
    __shared__ float ipPart[32 * 4];
    int u[cK]; int U = 0;
    for (int k = 0; k < cK; ++k) {
        int v = oidx[b * cK + k];
        bool dup = false;
        for (int j = 0; j < U; ++j) dup = dup || (u[j] == v);
        if (!dup) u[U++] = v;
    }
    for (int i = 1; i < U; ++i) {
        int key = u[i], j = i - 1;
        while (j >= 0 && u[j] > key) { u[j + 1] = u[j]; --j; }
        u[j + 1] = key;
    }
    unsigned long long m0 = 0, m1 = 0;
    for (int k = 0; k < U; ++k) {
        int v = u[k];
        if (v < 64) m0 |= 1ull << v; else m1 |= 1ull << (v - 64);
    }
    int ui[cK]; float prO[cK];
    #pragma unroll
    for (int k = 0; k < cK; ++k) ui[k] = (k < U) ? u[k] : 0;
    #pragma unroll
    for (int k = 0; k < cK; ++k) prO[k] = (k < U) ? projq[t * cD + ui[k]] : 0.0f;
    float qv = 0.0f;
    for (int d = 0; d < cD; ++d)
        qv = fmaf(query[h * cD + d], projs[d * cS + t], qv);
    const float* __restrict__ chunk = data + (size_t)b * (cN * cD) + half * (32 * cD);
    float acc[32];
    #pragma unroll
    for (int n = 0; n < 32; ++n) acc[n] = 0.0f;
    for (int dc = 0; dc < cD / 16; ++dc) {
        float pm[16];
        const float4* p4 = reinterpret_cast<const float4*>(projq + t * cD + dc * 16);
        #pragma unroll
        for (int j = 0; j < 4; ++j) {
            float4 v = p4[j];
            float tmp[4] = { v.x, v.y, v.z, v.w };
            #pragma unroll
            for (int e = 0; e < 4; ++e) {
                int d = dc * 16 + j * 4 + e;
                bool msk = (((d < 64) ? (m0 >> d) : (m1 >> (d - 64))) & 1ull) != 0;
                pm[j * 4 + e] = msk ? 0.0f : tmp[e];
            }
        }
        #pragma unroll
        for (int n = 0; n < 32; ++n) {
            const float* __restrict__ r = chunk + n * cD + dc * 16;
            #pragma unroll
            for (int i = 0; i < 16; ++i)
                acc[n] = fmaf(r[i], pm[i], acc[n]);
        }
    }
    #pragma unroll
    for (int n = 0; n < 32; ++n) {
        const int nn = half * 32 + n;
        const float* __restrict__ r = chunk + n * cD;
        float o = 0.0f;
        #pragma unroll
        for (int k = 0; k < cK; ++k)
            o = fmaf((k < U) ? r[ui[k]] : 0.0f, prO[k], o);
        const bool bitIn = acc[n] > 0.0f;
        unsigned long long mIn = __ballot(bitIn);
        unsigned long long mOut = __ballot(o > 0.0f);
        float v = bitIn ? qv : -qv;
        #pragma unroll
        for (int off = 32; off > 0; off >>= 1) v += __shfl_down(v, off);
        if (lane == 0) ipPart[n * 4 + w] = v;
        if (lane < 8) {
            out[(size_t)b * (cN * 32) + nn * 32 + w * 8 + lane] =
                (float)((mIn >> (8 * lane)) & 0xFFull);
            if (w < 2)
                out[HASH_OUT_BASE + (size_t)b * (cN * 16) + nn * 16 + w * 8 + lane] =
                    (float)((mOut >> (8 * lane)) & 0xFFull);
        }
    }
    __syncthreads();
    if (t < 32) {
        float ip = ipPart[t * 4 + 0] + ipPart[t * 4 + 1] + ipPart[t * 4 + 2] + ipPart[t * 4 + 3];
        out[SCORE_BASE + b * cN + half * 32 + t] = 0.0048957583f * norm_data[b * cN + half * 32 + t] * ip;
    }
}

extern "C" void kernel_launch(void* const* d_in, const int* in_sizes, int n_in,
                              void* d_out, int out_size, void* d_ws, size_t ws_size,
                              hipStream_t stream) {
    const float* data      = (const float*)d_in[0];
    const float* query     = (const float*)d_in[1];
    const int*   oidx      = (const int*)d_in[2];
    const float* norm_data = (const float*)d_in[3];
    // d_in[4] = norm_outlier: unused by the reference
    const float* projq     = (const float*)d_in[5];  // proj_dir_quant [S,D]
    const float* projs     = (const float*)d_in[6];  // proj_dir_score [D,S]
    float* out = (float*)d_out;

    if (ws_size >= WS_NEED) {
        float* qv  = (float*)d_ws;
        short* bhi = (short*)((char*)d_ws + WS_BHI);
        short* blo = (short*)((char*)d_ws + WS_BLO);
        qjl_qv<<<cH, cS, 0, stream>>>(query, projs, qv);
        qjl_bfrag<<<16, 256, 0, stream>>>(projq, bhi, blo);
        qjl_mfma<<<cH * cG, 256, 0, stream>>>(data, oidx, norm_data, projq,
                                              qv, bhi, blo, out);
    } else {
        qjl_valu<<<cH * cG * 2, 256, 0, stream>>>(data, query, oidx, norm_data,
                                                  projq, projs, out);
    }
}

// Round 21
// 160.164 us; speedup vs baseline: 2.8858x; 1.0038x over previous
//
#include <hip/hip_runtime.h>
#include <hip/hip_bf16.h>

// QJLSketch: H=32, G=128, N=64, D=128, S=256, K=8
// d_out (float32, concatenated):
//   [0,        8388608): hash_inlier  [32,128,64,32] byte values as floats
//   [8388608, 12582912): hash_outlier [32,128,64,16] byte values as floats
//   [12582912,12845056): scores       [32, 128*64]
//
// Strategy: bf16 hi/lo split MFMA GEMM (fast approx) + exact f32-chain fixup for
// |value| < EPS. Non-flagged signs provably match the reference's sequential
// f32 FMA chain; flagged ones recomputed with the verified chain semantics.
// R21 = R20 (champion, 160.8us) + (1) s_setprio(1) around the inlier MFMA
// cluster (T5: phase-diverse blocks/CU -> scheduler favors MFMA waves),
// (2) qv+bfrag merged into one pre-kernel (one fewer serialized launch).

typedef __attribute__((ext_vector_type(8))) short short8;
typedef __attribute__((ext_vector_type(4))) float f32x4;

constexpr int cH = 32, cG = 128, cN = 64, cD = 128, cS = 256, cK = 8;
constexpr int HASH_OUT_BASE = cH * cG * cN * (cS / 8);                  // 8388608
constexpr int SCORE_BASE    = HASH_OUT_BASE + cH * cG * cN * (cS / 16); // 12582912
constexpr float EPS_IN  = 1e-3f;
constexpr float EPS_OUT = 1e-3f;
constexpr size_t WS_BHI = 32768, WS_BLO = 98304, WS_NEED = 163840;

#define MFMA(a, b, c) __builtin_amdgcn_mfma_f32_16x16x32_bf16(a, b, c, 0, 0, 0)

// Truncation hi/lo split of a pair of f32 into packed bf16 dwords.
// hi = top16(x) (exact residual r = x - hi), lo = top16(r).
// |x - (hi+lo)| <= 2^-16 |x|  -- well inside the EPS fixup margin.
__device__ inline void split_pair(float x0, float x1, unsigned& hpk, unsigned& lpk) {
    unsigned u0 = __builtin_bit_cast(unsigned, x0);
    unsigned u1 = __builtin_bit_cast(unsigned, x1);
    unsigned h1 = u1 & 0xFFFF0000u;
    float hf0 = __builtin_bit_cast(float, u0 & 0xFFFF0000u);
    float hf1 = __builtin_bit_cast(float, h1);
    unsigned r0 = __builtin_bit_cast(unsigned, x0 - hf0);
    unsigned r1 = __builtin_bit_cast(unsigned, x1 - hf1);
    hpk = (u0 >> 16) | h1;
    lpk = (r0 >> 16) | (r1 & 0xFFFF0000u);
}

__device__ inline unsigned long long sel4(unsigned long long a0, unsigned long long a1,
                                          unsigned long long a2, unsigned long long a3, int r) {
    unsigned long long x = a0;
    x = (r == 1) ? a1 : x; x = (r == 2) ? a2 : x; x = (r == 3) ? a3 : x;
    return x;
}
__device__ inline int sel8(const int* u, int k) {
    int x = u[0];
    x = (k == 1) ? u[1] : x; x = (k == 2) ? u[2] : x; x = (k == 3) ? u[3] : x;
    x = (k == 4) ? u[4] : x; x = (k == 5) ? u[5] : x; x = (k == 6) ? u[6] : x;
    x = (k == 7) ? u[7] : x;
    return x;
}
#define CE(i, j) { int a = u[i], b = u[j]; u[i] = min(a, b); u[j] = max(a, b); }

#define SORT8_AND_MASK(oidx_ptr, bb)                                   \
    int u[cK];                                                         \
    _Pragma("unroll")                                                  \
    for (int k = 0; k < cK; ++k) u[k] = (oidx_ptr)[(bb) * cK + k];     \
    unsigned long long m0 = 0, m1 = 0;                                 \
    _Pragma("unroll")                                                  \
    for (int k = 0; k < cK; ++k) {                                     \
        int v = u[k];                                                  \
        if (v < 64) m0 |= 1ull << v; else m1 |= 1ull << (v - 64);      \
    }                                                                  \
    CE(0,1) CE(2,3) CE(4,5) CE(6,7)                                    \
    CE(0,2) CE(1,3) CE(4,6) CE(5,7)                                    \
    CE(1,2) CE(5,6)                                                    \
    CE(0,4) CE(1,5) CE(2,6) CE(3,7)                                    \
    CE(2,4) CE(3,5)                                                    \
    CE(1,2) CE(3,4) CE(5,6)

// Exact reference chain for one (row,s) inlier value (rare). Vectorized.
__device__ __attribute__((noinline)) float exact_inlier(
    const float* __restrict__ dr, const float* __restrict__ pr,
    unsigned long long m0, unsigned long long m1)
{
    float ex = 0.0f;
    #pragma unroll 1
    for (int dc = 0; dc < 4; ++dc) {
        float4 da[8], pa[8];
        #pragma unroll
        for (int j = 0; j < 8; ++j) {
            da[j] = reinterpret_cast<const float4*>(dr)[dc * 8 + j];
            pa[j] = reinterpret_cast<const float4*>(pr)[dc * 8 + j];
        }
        #pragma unroll
        for (int j = 0; j < 8; ++j) {
            float dv[4] = { da[j].x, da[j].y, da[j].z, da[j].w };
            float pv[4] = { pa[j].x, pa[j].y, pa[j].z, pa[j].w };
            #pragma unroll
            for (int e = 0; e < 4; ++e) {
                const int d = dc * 32 + j * 4 + e;
                const bool msk = ((((d < 64) ? (m0 >> d) : (m1 >> (d - 64))) & 1ull) != 0);
                ex = fmaf(dv[e], msk ? 0.0f : pv[e], ex);
            }
        }
    }
    return ex;
}

// --- merged precompute: blocks 0..31 -> sketched_q[h][s]; 32..47 -> B frags ---
__global__ __launch_bounds__(256) void qjl_pre(
    const float* __restrict__ query, const float* __restrict__ projs,
    const float* __restrict__ projq, float* __restrict__ qv_out,
    short* __restrict__ bhi, short* __restrict__ blo)
{
    const int t = threadIdx.x;
    if (blockIdx.x < 32) {
        const int h = blockIdx.x, s = t;
        float qa = 0.0f;
        for (int d = 0; d < cD; ++d)
            qa = fmaf(query[h * cD + d], projs[d * cS + s], qa);
        qv_out[h * cS + s] = qa;
    } else {
        const int idx = (blockIdx.x - 32) * 256 + t;   // [0, 4096)
        const int l = idx & 63, nt = (idx >> 6) & 15, ksub = idx >> 10;
        const int s = nt * 16 + (l & 15);
        const int k0 = ksub * 32 + (l >> 4) * 8;
        unsigned* bh32 = reinterpret_cast<unsigned*>(bhi);
        unsigned* bl32 = reinterpret_cast<unsigned*>(blo);
        #pragma unroll
        for (int e = 0; e < 4; ++e) {
            float x0 = projq[s * cD + k0 + 2 * e];
            float x1 = projq[s * cD + k0 + 2 * e + 1];
            unsigned hp, lp;
            split_pair(x0, x1, hp, lp);
            bh32[idx * 4 + e] = hp;
            bl32[idx * 4 + e] = lp;
        }
    }
}

__global__ __launch_bounds__(256, 3) void qjl_mfma(
    const float* __restrict__ data, const int* __restrict__ oidx,
    const float* __restrict__ norm_data, const float* __restrict__ projq,
    const float* __restrict__ qv_ws, const short* __restrict__ bhi_ws,
    const short* __restrict__ blo_ws, float* __restrict__ out)
{
    const int b    = blockIdx.x;      // h*G + g
    const int t    = threadIdx.x;
    const int lane = t & 63;
    const int w    = t >> 6;          // wave owns nt = 4w..4w+3 (s in [64w, 64w+64))
    const int c0   = lane & 15;
    const int g16  = lane >> 4;
    const int h    = b >> 7;

    __shared__ char  A_buf[32768];          // 32 KB: A_hi/A_lo, then hash staging
    __shared__ float dO[cK * cN];           // 2 KB   [k][row]
    __shared__ float pO[cK * 128];          // 4 KB   [k][s<128]
    __shared__ float ipPart[cN * 4];        // 1 KB
    short* A_hi  = reinterpret_cast<short*>(A_buf);
    short* A_lo  = reinterpret_cast<short*>(A_buf + 16384);
    float* hashI = reinterpret_cast<float*>(A_buf);            // [64][33] = 8448 B
    float* hashO = reinterpret_cast<float*>(A_buf + 16384);    // [64][17] = 4352 B

    const f32x4 zero4 = { 0.f, 0.f, 0.f, 0.f };

    SORT8_AND_MASK(oidx, b)
    const float* __restrict__ chunk = data + (size_t)b * (cN * cD);

    // --- stage A (masked, hi/lo trunc-split) in fragment slot order ---
    #pragma unroll
    for (int i = 0; i < 4; ++i) {
        const int slot = i * 256 + t;
        const int l = slot & 63, frag = slot >> 6;
        const int mt = frag & 3, ksub = frag >> 2;
        const int row = mt * 16 + (l & 15);
        const int k0 = ksub * 32 + (l >> 4) * 8;
        const float4* p = reinterpret_cast<const float4*>(chunk + row * cD + k0);
        float4 v0 = p[0], v1 = p[1];
        float xs[8] = { v0.x, v0.y, v0.z, v0.w, v1.x, v1.y, v1.z, v1.w };
        const unsigned bits = (unsigned)(((k0 < 64) ? (m0 >> k0) : (m1 >> (k0 - 64))) & 0xFFull);
        unsigned hp[4], lp[4];
        #pragma unroll
        for (int e = 0; e < 4; ++e) {
            float x0 = ((bits >> (2 * e)) & 1u) ? 0.0f : xs[2 * e];
            float x1 = ((bits >> (2 * e + 1)) & 1u) ? 0.0f : xs[2 * e + 1];
            split_pair(x0, x1, hp[e], lp[e]);
        }
        *reinterpret_cast<uint4*>(&A_hi[slot * 8]) = uint4{ hp[0], hp[1], hp[2], hp[3] };
        *reinterpret_cast<uint4*>(&A_lo[slot * 8]) = uint4{ lp[0], lp[1], lp[2], lp[3] };
    }
    // --- stage dO[k][row] (512 elems, 2/thread) ---
    #pragma unroll
    for (int i = 0; i < 2; ++i) {
        const int idx = i * 256 + t;
        const int k = idx >> 6, row = idx & 63;
        dO[idx] = chunk[row * cD + sel8(u, k)];
    }
    // --- stage pO[k][s<128] (1024 elems, 4/thread; dup slots -> 0) ---
    #pragma unroll
    for (int i = 0; i < 4; ++i) {
        const int idx = i * 256 + t;
        const int k = idx >> 7, s = idx & 127;
        const int uk = sel8(u, k);
        const bool dup = (k > 0) && (uk == sel8(u, k - 1));
        float x = projq[s * cD + uk];
        pO[idx] = dup ? 0.0f : x;
    }
    __syncthreads();

    // --- inlier GEMM: sk_in directly (A masked). K'=384: hi*Bhi, hi*Blo, lo*Bhi ---
    f32x4 acc[16];
    #pragma unroll
    for (int i = 0; i < 16; ++i)
        acc[i] = zero4;

    __builtin_amdgcn_s_setprio(1);
    #pragma unroll
    for (int ksub = 0; ksub < 4; ++ksub) {
        short8 ah[4], al[4];
        #pragma unroll
        for (int mt = 0; mt < 4; ++mt) {
            ah[mt] = *reinterpret_cast<const short8*>(&A_hi[((ksub * 4 + mt) * 64 + lane) * 8]);
            al[mt] = *reinterpret_cast<const short8*>(&A_lo[((ksub * 4 + mt) * 64 + lane) * 8]);
        }
        #pragma unroll
        for (int q = 0; q < 4; ++q) {
            short8 bh = *reinterpret_cast<const short8*>(
                &bhi_ws[((ksub * 16 + w * 4 + q) * 64 + lane) * 8]);
            #pragma unroll
            for (int mt = 0; mt < 4; ++mt)
                acc[mt * 4 + q] = MFMA(ah[mt], bh, acc[mt * 4 + q]);
            short8 bl = *reinterpret_cast<const short8*>(
                &blo_ws[((ksub * 16 + w * 4 + q) * 64 + lane) * 8]);
            #pragma unroll
            for (int mt = 0; mt < 4; ++mt)
                acc[mt * 4 + q] = MFMA(ah[mt], bl, acc[mt * 4 + q]);
            #pragma unroll
            for (int mt = 0; mt < 4; ++mt)
                acc[mt * 4 + q] = MFMA(al[mt], bh, acc[mt * 4 + q]);
        }
    }
    __builtin_amdgcn_s_setprio(0);

    __syncthreads();   // all A_hi/A_lo reads done -> A_buf becomes hash staging

    // --- inlier epilogue: fixup + ballots + ip partials; bytes -> hashI LDS ---
    float qvv[4];
    #pragma unroll
    for (int q = 0; q < 4; ++q)
        qvv[q] = qv_ws[h * cS + (w * 4 + q) * 16 + c0];

    #pragma unroll
    for (int mt = 0; mt < 4; ++mt) {
        float part[4] = { 0.f, 0.f, 0.f, 0.f };
        #pragma unroll
        for (int q = 0; q < 4; ++q) {
            unsigned long long b0, b1, b2, b3;
            #pragma unroll
            for (int r = 0; r < 4; ++r) {
                float v = acc[mt * 4 + q][r];
                if (fabsf(v) < EPS_IN) {
                    int row = mt * 16 + 4 * g16 + r;
                    int s = (w * 4 + q) * 16 + c0;
                    v = exact_inlier(chunk + row * cD, projq + s * cD, m0, m1);
                }
                bool bit = v > 0.0f;
                unsigned long long bal = __ballot(bit);
                part[r] += bit ? qvv[q] : -qvv[q];
                if (r == 0) b0 = bal; else if (r == 1) b1 = bal;
                else if (r == 2) b2 = bal; else b3 = bal;
            }
            if (lane < 32) {
                int r = lane & 3, g = (lane >> 2) & 3, hb = lane >> 4;
                unsigned long long bb = sel4(b0, b1, b2, b3, r);
                int row = mt * 16 + 4 * g + r;
                hashI[row * 33 + (w * 4 + q) * 2 + hb] =
                    (float)((bb >> (16 * g + 8 * hb)) & 0xFFull);
            }
        }
        #pragma unroll
        for (int r = 0; r < 4; ++r) {
            float x = part[r];
            x += __shfl_xor(x, 1); x += __shfl_xor(x, 2);
            x += __shfl_xor(x, 4); x += __shfl_xor(x, 8);
            if (c0 == 0) ipPart[(mt * 16 + 4 * g16 + r) * 4 + w] = x;
        }
    }

    // --- outlier phase: ALL 4 waves, ntq = 2w+q (s < 128); bytes -> hashO LDS ---
    {
        short8 aO[4];
        #pragma unroll
        for (int mt = 0; mt < 4; ++mt) {
            unsigned pk[4];
            #pragma unroll
            for (int e = 0; e < 4; ++e) {
                float x0 = dO[(2 * e) * cN + mt * 16 + c0];
                float x1 = dO[(2 * e + 1) * cN + mt * 16 + c0];
                unsigned hp, lp;
                split_pair(x0, x1, hp, lp);
                pk[e] = (g16 == 2) ? lp : ((g16 == 3) ? 0u : hp);
            }
            aO[mt] = __builtin_bit_cast(short8, uint4{ pk[0], pk[1], pk[2], pk[3] });
        }
        #pragma unroll
        for (int q = 0; q < 2; ++q) {
            const int ntq = 2 * w + q;
            const int s = ntq * 16 + c0;
            unsigned pk[4];
            #pragma unroll
            for (int e = 0; e < 4; ++e) {
                float x0 = pO[(2 * e) * 128 + s];
                float x1 = pO[(2 * e + 1) * 128 + s];
                unsigned hp, lp;
                split_pair(x0, x1, hp, lp);
                pk[e] = (g16 == 1) ? lp : ((g16 == 3) ? 0u : hp);
            }
            short8 bO = __builtin_bit_cast(short8, uint4{ pk[0], pk[1], pk[2], pk[3] });
            #pragma unroll
            for (int mt = 0; mt < 4; ++mt) {
                f32x4 accO = MFMA(aO[mt], bO, zero4);
                unsigned long long b0, b1, b2, b3;
                #pragma unroll
                for (int r = 0; r < 4; ++r) {
                    float v = accO[r];
                    if (fabsf(v) < EPS_OUT) {
                        int row = mt * 16 + 4 * g16 + r;
                        float o = 0.0f;
                        #pragma unroll
                        for (int k = 0; k < cK; ++k)
                            o = fmaf(dO[k * cN + row], pO[k * 128 + s], o);
                        v = o;
                    }
                    unsigned long long bal = __ballot(v > 0.0f);
                    if (r == 0) b0 = bal; else if (r == 1) b1 = bal;
                    else if (r == 2) b2 = bal; else b3 = bal;
                }
                if (lane < 32) {
                    int r = lane & 3, g = (lane >> 2) & 3, hb = lane >> 4;
                    unsigned long long bb = sel4(b0, b1, b2, b3, r);
                    int row = mt * 16 + 4 * g + r;
                    hashO[row * 17 + ntq * 2 + hb] =
                        (float)((bb >> (16 * g + 8 * hb)) & 0xFFull);
                }
            }
        }
    }
    __syncthreads();

    // --- coalesced dump: hashI (8/thread), hashO (4/thread), scores ---
    #pragma unroll
    for (int i = 0; i < 2; ++i) {
        const int base = t * 8 + i * 4;            // 4 consecutive, same row
        const int row = base >> 5, col = base & 31;
        float4 v;
        v.x = hashI[row * 33 + col + 0];
        v.y = hashI[row * 33 + col + 1];
        v.z = hashI[row * 33 + col + 2];
        v.w = hashI[row * 33 + col + 3];
        reinterpret_cast<float4*>(out + (size_t)b * (cN * 32))[t * 2 + i] = v;
    }
    {
        const int base = t * 4;                    // 4 consecutive, same row
        const int row = base >> 4, col = base & 15;
        float4 v;
        v.x = hashO[row * 17 + col + 0];
        v.y = hashO[row * 17 + col + 1];
        v.z = hashO[row * 17 + col + 2];
        v.w = hashO[row * 17 + col + 3];
        reinterpret_cast<float4*>(out + HASH_OUT_BASE + (size_t)b * (cN * 16))[t] = v;
    }
    if (t < cN) {
        float ip = ipPart[t * 4 + 0] + ipPart[t * 4 + 1]
                 + ipPart[t * 4 + 2] + ipPart[t * 4 + 3];
        const float scl = 0.0048957583f;   // sqrt(pi/2)/256
        out[SCORE_BASE + (size_t)b * cN + t] = scl * norm_data[b * cN + t] * ip;
    }
}

// ---------------- fallback (R3 kernel, passed): used if ws too small ----------------
__global__ __launch_bounds__(256) void qjl_valu(
    const float* __restrict__ data, const float* __restrict__ query,
    const int* __restrict__ oidx, const float* __restrict__ norm_data,
    const float* __restrict__ projq, const float* __restrict__ projs,
    float* __restrict__ out)
{
    const int b2 = blockIdx.x, b = b2 >> 1, half = b2 & 1;
    const int t = threadIdx.x, lane = t & 63, w = t >> 6, h = b >> 7;
    __shared__ float ipPart[32 * 4];
    int u[cK]; int U = 0;
    for (int k = 0; k < cK; ++k) {
        int v = oidx[b * cK + k];
        bool dup = false;
        for (int j = 0; j < U; ++j) dup = dup || (u[j] == v);
        if (!dup) u[U++] = v;
    }
    for (int i = 1; i < U; ++i) {
        int key = u[i], j = i - 1;
        while (j >= 0 && u[j] > key) { u[j + 1] = u[j]; --j; }
        u[j + 1] = key;
    }
    unsigned long long m0 = 0, m1 = 0;
    for (int k = 0; k < U; ++k) {
        int v = u[k];
        if (v < 64) m0 |= 1ull << v; else m1 |= 1ull << (v - 64);
    }
    int ui[cK]; float prO[cK];
    #pragma unroll
    for (int k = 0; k < cK; ++k) ui[k] = (k < U) ? u[k] : 0;
    #pragma unroll
    for (int k = 0; k < cK; ++k) prO[k] = (k < U) ? projq[t * cD + ui[k]] : 0.0f;
    float qv = 0.0f;
    for (int d = 0; d < cD; ++d)
        qv = fmaf(query[h * cD + d], projs[d * cS + t], qv);
    const float* __restrict__ chunk = data + (size_t)b * (cN * cD) + half * (32 * cD);
    float acc[32];
    #pragma unroll
    for (int n = 0; n < 32; ++n) acc[n] = 0.0f;
    for (int dc = 0; dc < cD / 16; ++dc) {
        float pm[16];
        const float4* p4 = reinterpret_cast<const float4*>(projq + t * cD + dc * 16);
        #pragma unroll
        for (int j = 0; j < 4; ++j) {
            float4 v = p4[j];
            float tmp[4] = { v.x, v.y, v.z, v.w };
            #pragma unroll
            for (int e = 0; e < 4; ++e) {
                int d = dc * 16 + j * 4 + e;
                bool msk = (((d < 64) ? (m0 >> d) : (m1 >> (d - 64))) & 1ull) != 0;
                pm[j * 4 + e] = msk ? 0.0f : tmp[e];
            }
        }
        #pragma unroll
        for (int n = 0; n < 32; ++n) {
            const float* __restrict__ r = chunk + n * cD + dc * 16;
            #pragma unroll
            for (int i = 0; i < 16; ++i)
                acc[n] = fmaf(r[i], pm[i], acc[n]);
        }
    }
    #pragma unroll
    for (int n = 0; n < 32; ++n) {
        const int nn = half * 32 + n;
        const float* __restrict__ r = chunk + n * cD;
        float o = 0.0f;
        #pragma unroll
        for (int k = 0; k < cK; ++k)
            o = fmaf((k < U) ? r[ui[k]] : 0.0f, prO[k], o);
        const bool bitIn = acc[n] > 0.0f;
        unsigned long long mIn = __ballot(bitIn);
        unsigned long long mOut = __ballot(o > 0.0f);
        float v = bitIn ? qv : -qv;
        #pragma unroll
        for (int off = 32; off > 0; off >>= 1) v += __shfl_down(v, off);
        if (lane == 0) ipPart[n * 4 + w] = v;
        if (lane < 8) {
            out[(size_t)b * (cN * 32) + nn * 32 + w * 8 + lane] =
                (float)((mIn >> (8 * lane)) & 0xFFull);
            if (w < 2)
                out[HASH_OUT_BASE + (size_t)b * (cN * 16) + nn * 16 + w * 8 + lane] =
                    (float)((mOut >> (8 * lane)) & 0xFFull);
        }
    }
    __syncthreads();
    if (t < 32) {
        float ip = ipPart[t * 4 + 0] + ipPart[t * 4 + 1] + ipPart[t * 4 + 2] + ipPart[t * 4 + 3];
        out[SCORE_BASE + b * cN + half * 32 + t] = 0.0048957583f * norm_data[b * cN + half * 32 + t] * ip;
    }
}

extern "C" void kernel_launch(void* const* d_in, const int* in_sizes, int n_in,
                              void* d_out, int out_size, void* d_ws, size_t ws_size,
                              hipStream_t stream) {
    const float* data      = (const float*)d_in[0];
    const float* query     = (const float*)d_in[1];
    const int*   oidx      = (const int*)d_in[2];
    const float* norm_data = (const float*)d_in[3];
    // d_in[4] = norm_outlier: unused by the reference
    const float* projq     = (const float*)d_in[5];  // proj_dir_quant [S,D]
    const float* projs     = (const float*)d_in[6];  // proj_dir_score [D,S]
    float* out = (float*)d_out;

    if (ws_size >= WS_NEED) {
        float* qv  = (float*)d_ws;
        short* bhi = (short*)((char*)d_ws + WS_BHI);
        short* blo = (short*)((char*)d_ws + WS_BLO);
        qjl_pre<<<48, 256, 0, stream>>>(query, projs, projq, qv, bhi, blo);
        qjl_mfma<<<cH * cG, 256, 0, stream>>>(data, oidx, norm_data, projq,
                                              qv, bhi, blo, out);
    } else {
        qjl_valu<<<cH * cG * 2, 256, 0, stream>>>(data, query, oidx, norm_data,
                                                  projq, projs, out);
    }
}